// Round 2
// baseline (219.817 us; speedup 1.0000x reference)
//
#include <hip/hip_runtime.h>

#define HH 512
#define WW 512
#define ROWS 8
#define W4 (WW/4)          // 128 words per gray row
#define CH_STRIDE (HH*WW)
#define IMG_STRIDE (3*HH*WW)
#define NCHUNK (HH/ROWS)   // 64

// quantize one channel value: floor(clip(v*255, 0, 255))
__device__ __forceinline__ float quant(float v) {
    return floorf(fminf(fmaxf(v * 255.0f, 0.0f), 255.0f));
}

// 4 gray pixels (rounded, cv2 RGB2GRAY weights) at row gr, cols 4*wq..4*wq+3
// KEEP BIT-IDENTICAL to the validated R1 expression.
__device__ __forceinline__ float4 gray4(const float* __restrict__ img, int gr, int wq) {
    const float4 r = reinterpret_cast<const float4*>(img + 0 * CH_STRIDE + gr * WW)[wq];
    const float4 g = reinterpret_cast<const float4*>(img + 1 * CH_STRIDE + gr * WW)[wq];
    const float4 b = reinterpret_cast<const float4*>(img + 2 * CH_STRIDE + gr * WW)[wq];
    float4 o;
    o.x = rintf(0.299f * quant(r.x) + 0.587f * quant(g.x) + 0.114f * quant(b.x));
    o.y = rintf(0.299f * quant(r.y) + 0.587f * quant(g.y) + 0.114f * quant(b.y));
    o.z = rintf(0.299f * quant(r.z) + 0.587f * quant(g.z) + 0.114f * quant(b.z));
    o.w = rintf(0.299f * quant(r.w) + 0.587f * quant(g.w) + 0.114f * quant(b.w));
    return o;
}

__device__ __forceinline__ unsigned pack4(float4 o) {
    return (unsigned)o.x | ((unsigned)o.y << 8) | ((unsigned)o.z << 16) | ((unsigned)o.w << 24);
}

// 4 rounded sobel-avg values (exact integer path) for word w4v of LDS row lr
__device__ __forceinline__ void sobel4(const unsigned* __restrict__ g, int lr, int w4v, int out[4]) {
    const unsigned c0 = g[(lr - 1) * W4 + w4v];
    const unsigned c1 = g[lr * W4 + w4v];
    const unsigned c2 = g[(lr + 1) * W4 + w4v];
    const unsigned lw = g[lr * W4 + (w4v == 0 ? 0 : w4v - 1)];
    const unsigned rw = g[lr * W4 + (w4v == W4 - 1 ? W4 - 1 : w4v + 1)];

    int gx[6];
    // reflect101 at image edges: left neighbor of px0 is px1; right of px511 is px510
    gx[0] = (w4v == 0) ? (int)((c1 >> 8) & 255u) : (int)(lw >> 24);
    gx[1] = (int)(c1 & 255u);
    gx[2] = (int)((c1 >> 8) & 255u);
    gx[3] = (int)((c1 >> 16) & 255u);
    gx[4] = (int)(c1 >> 24);
    gx[5] = (w4v == W4 - 1) ? (int)((c1 >> 16) & 255u) : (int)(rw & 255u);

#pragma unroll
    for (int j = 0; j < 4; ++j) {
        const int sx = __builtin_abs(gx[j + 2] - gx[j]);
        const int sy = __builtin_abs((int)((c2 >> (8 * j)) & 255u) - (int)((c0 >> (8 * j)) & 255u));
        const int s = sx + sy;
        // round-half-even of s/2
        out[j] = (s >> 1) + ((s & 1) & ((s >> 1) & 1));
    }
}

__global__ __launch_bounds__(256, 8) void sobel_loss_kernel(
    const float* __restrict__ pred, const float* __restrict__ gt_,
    float* __restrict__ out)
{
    // packed uint8 gray tiles: (ROWS+2) rows x 128 words x 2 images = 10 KiB
    __shared__ unsigned gp[(ROWS + 2) * W4];
    __shared__ unsigned gq[(ROWS + 2) * W4];
    __shared__ int red[4];

    const int blk   = blockIdx.x;
    const int b     = blk >> 6;        // / NCHUNK
    const int chunk = blk & (NCHUNK - 1);
    const int r0    = chunk * ROWS;

    const float* P = pred + (size_t)b * IMG_STRIDE;
    const float* T = gt_  + (size_t)b * IMG_STRIDE;

    // ---- fill gray LDS: rows r0-1 .. r0+ROWS (BORDER_REFLECT_101) ----
    for (int i4 = threadIdx.x; i4 < (ROWS + 2) * W4; i4 += 256) {
        const int lr = i4 >> 7;          // / W4
        const int wq = i4 & (W4 - 1);
        int gr = r0 - 1 + lr;
        gr = (gr < 0) ? 1 : ((gr > HH - 1) ? 2 * (HH - 1) - gr : gr);
        gp[i4] = pack4(gray4(P, gr, wq));
        gq[i4] = pack4(gray4(T, gr, wq));
    }
    __syncthreads();

    // ---- integer sobel + |diff| accumulate (exact) ----
    int acc = 0;
    for (int idx = threadIdx.x; idx < ROWS * W4; idx += 256) {
        const int lr  = (idx >> 7) + 1;   // LDS row 1..ROWS
        const int w4v = idx & (W4 - 1);
        int sp[4], st[4];
        sobel4(gp, lr, w4v, sp);
        sobel4(gq, lr, w4v, st);
#pragma unroll
        for (int j = 0; j < 4; ++j)
            acc += __builtin_abs(sp[j] - st[j]);
    }

    // ---- reduce: wave shuffle, then cross-wave ----
    for (int off = 32; off > 0; off >>= 1)
        acc += __shfl_down(acc, off, 64);

    const int lane = threadIdx.x & 63;
    const int wid  = threadIdx.x >> 6;
    if (lane == 0) red[wid] = acc;
    __syncthreads();
    if (threadIdx.x == 0) {
        const int s = red[0] + red[1] + red[2] + red[3];
        // mean over 32*512*512 elements, then /255
        atomicAdd(out, (float)s * (1.0f / (255.0f * 32.0f * 512.0f * 512.0f)));
    }
}

extern "C" void kernel_launch(void* const* d_in, const int* in_sizes, int n_in,
                              void* d_out, int out_size, void* d_ws, size_t ws_size,
                              hipStream_t stream) {
    const float* y_pred = (const float*)d_in[0];
    const float* y_true = (const float*)d_in[1];
    float* out = (float*)d_out;

    // harness re-poisons d_out with 0xAA before every timed launch
    hipMemsetAsync(out, 0, out_size * sizeof(float), stream);

    const int nblk = 32 * NCHUNK;   // one block per (batch, 8-row strip)
    sobel_loss_kernel<<<nblk, 256, 0, stream>>>(y_pred, y_true, out);
}

// Round 3
// 214.867 us; speedup vs baseline: 1.0230x; 1.0230x over previous
//
#include <hip/hip_runtime.h>

#define HH 512
#define WW 512
#define ROWS 8
#define W4 (WW/4)          // 128 words per gray row
#define CH_STRIDE (HH*WW)
#define IMG_STRIDE (3*HH*WW)
#define NCHUNK (HH/ROWS)   // 64

// quantize one channel value: floor(clip(v*255, 0, 255))
__device__ __forceinline__ float quant(float v) {
    return floorf(fminf(fmaxf(v * 255.0f, 0.0f), 255.0f));
}

// pack 4 gray pixels (rounded, cv2 RGB2GRAY weights) into one word.
// KEEP the arithmetic BIT-IDENTICAL to the validated R1/R2 expression.
__device__ __forceinline__ unsigned pack_gray(float4 r, float4 g, float4 b) {
    const unsigned o0 = (unsigned)rintf(0.299f * quant(r.x) + 0.587f * quant(g.x) + 0.114f * quant(b.x));
    const unsigned o1 = (unsigned)rintf(0.299f * quant(r.y) + 0.587f * quant(g.y) + 0.114f * quant(b.y));
    const unsigned o2 = (unsigned)rintf(0.299f * quant(r.z) + 0.587f * quant(g.z) + 0.114f * quant(b.z));
    const unsigned o3 = (unsigned)rintf(0.299f * quant(r.w) + 0.587f * quant(g.w) + 0.114f * quant(b.w));
    return o0 | (o1 << 8) | (o2 << 16) | (o3 << 24);
}

// 4 rounded sobel-avg values (exact integer path) for word w4v of LDS row lr
__device__ __forceinline__ void sobel4(const unsigned* __restrict__ g, int lr, int w4v, int out[4]) {
    const unsigned c0 = g[(lr - 1) * W4 + w4v];
    const unsigned c1 = g[lr * W4 + w4v];
    const unsigned c2 = g[(lr + 1) * W4 + w4v];
    const unsigned lw = g[lr * W4 + (w4v == 0 ? 0 : w4v - 1)];
    const unsigned rw = g[lr * W4 + (w4v == W4 - 1 ? W4 - 1 : w4v + 1)];

    int gx[6];
    // reflect101 at image edges: left neighbor of px0 is px1; right of px511 is px510
    gx[0] = (w4v == 0) ? (int)((c1 >> 8) & 255u) : (int)(lw >> 24);
    gx[1] = (int)(c1 & 255u);
    gx[2] = (int)((c1 >> 8) & 255u);
    gx[3] = (int)((c1 >> 16) & 255u);
    gx[4] = (int)(c1 >> 24);
    gx[5] = (w4v == W4 - 1) ? (int)((c1 >> 16) & 255u) : (int)(rw & 255u);

#pragma unroll
    for (int j = 0; j < 4; ++j) {
        const int sx = __builtin_abs(gx[j + 2] - gx[j]);
        const int sy = __builtin_abs((int)((c2 >> (8 * j)) & 255u) - (int)((c0 >> (8 * j)) & 255u));
        const int s = sx + sy;
        // round-half-even of s/2
        out[j] = (s >> 1) + ((s & 1) & ((s >> 1) & 1));
    }
}

__global__ __launch_bounds__(256) void sobel_loss_kernel(
    const float* __restrict__ pred, const float* __restrict__ gt_,
    float* __restrict__ out)
{
    // packed uint8 gray tiles: (ROWS+2) rows x 128 words x 2 images = 10 KiB
    __shared__ unsigned gp[(ROWS + 2) * W4];
    __shared__ unsigned gq[(ROWS + 2) * W4];
    __shared__ int red[4];

    const int blk   = blockIdx.x;
    const int b     = blk >> 6;        // / NCHUNK
    const int chunk = blk & (NCHUNK - 1);
    const int r0    = chunk * ROWS;

    const float* P = pred + (size_t)b * IMG_STRIDE;
    const float* T = gt_  + (size_t)b * IMG_STRIDE;

    const int wq  = threadIdx.x & (W4 - 1);   // word column 0..127
    const int lrb = threadIdx.x >> 7;         // row-group base: 0 or 1

    // ---- precompute the 5 source-row offsets (BORDER_REFLECT_101) ----
    int goff[5];
#pragma unroll
    for (int k = 0; k < 5; ++k) {
        int gr = r0 - 1 + lrb + 2 * k;        // LDS rows lrb, lrb+2, ..., lrb+8
        gr = (gr < 0) ? 1 : ((gr > HH - 1) ? 2 * (HH - 1) - gr : gr);
        goff[k] = gr * WW;
    }

    // ---- issue ALL 30 float4 loads before any processing (max MLP) ----
    float4 vp[5][3], vt[5][3];
#pragma unroll
    for (int k = 0; k < 5; ++k)
#pragma unroll
        for (int c = 0; c < 3; ++c)
            vp[k][c] = reinterpret_cast<const float4*>(P + c * CH_STRIDE + goff[k])[wq];
#pragma unroll
    for (int k = 0; k < 5; ++k)
#pragma unroll
        for (int c = 0; c < 3; ++c)
            vt[k][c] = reinterpret_cast<const float4*>(T + c * CH_STRIDE + goff[k])[wq];
    // pin: no load may be sunk past this point by the scheduler
    __builtin_amdgcn_sched_barrier(0);

    // ---- gray-pack P (waits only on P loads; T loads still in flight), then T ----
#pragma unroll
    for (int k = 0; k < 5; ++k) {
        const int di = (lrb + 2 * k) * W4 + wq;
        gp[di] = pack_gray(vp[k][0], vp[k][1], vp[k][2]);
    }
#pragma unroll
    for (int k = 0; k < 5; ++k) {
        const int di = (lrb + 2 * k) * W4 + wq;
        gq[di] = pack_gray(vt[k][0], vt[k][1], vt[k][2]);
    }
    __syncthreads();

    // ---- integer sobel + |diff| accumulate (exact) ----
    int acc = 0;
#pragma unroll
    for (int j = 0; j < 4; ++j) {
        const int lr = lrb + 2 * j + 1;       // LDS row 1..ROWS
        int sp[4], st[4];
        sobel4(gp, lr, wq, sp);
        sobel4(gq, lr, wq, st);
#pragma unroll
        for (int t = 0; t < 4; ++t)
            acc += __builtin_abs(sp[t] - st[t]);
    }

    // ---- reduce: wave shuffle, then cross-wave ----
    for (int off = 32; off > 0; off >>= 1)
        acc += __shfl_down(acc, off, 64);

    const int lane = threadIdx.x & 63;
    const int wid  = threadIdx.x >> 6;
    if (lane == 0) red[wid] = acc;
    __syncthreads();
    if (threadIdx.x == 0) {
        const int s = red[0] + red[1] + red[2] + red[3];
        // mean over 32*512*512 elements, then /255
        atomicAdd(out, (float)s * (1.0f / (255.0f * 32.0f * 512.0f * 512.0f)));
    }
}

extern "C" void kernel_launch(void* const* d_in, const int* in_sizes, int n_in,
                              void* d_out, int out_size, void* d_ws, size_t ws_size,
                              hipStream_t stream) {
    const float* y_pred = (const float*)d_in[0];
    const float* y_true = (const float*)d_in[1];
    float* out = (float*)d_out;

    // harness re-poisons d_out with 0xAA before every timed launch
    hipMemsetAsync(out, 0, out_size * sizeof(float), stream);

    const int nblk = 32 * NCHUNK;   // one block per (batch, 8-row strip)
    sobel_loss_kernel<<<nblk, 256, 0, stream>>>(y_pred, y_true, out);
}